// Round 16
// baseline (98.015 us; speedup 1.0000x reference)
//
#include <hip/hip_runtime.h>
#include <cstdint>
#include <cstddef>

#define DIMX  1024
#define NH    8
#define HD    64
#define QKD   512            // NH*HD
#define VDD   128            // DIMX/NH
#define BATCH 4
#define SEQ   1024
#define NPOS  (BATCH*SEQ)    // 4096
#define TW    (2*QKD + DIMX) // 2048
#define SCALE 0.125f         // HD^-0.5 (folded into Qb at pack time)

typedef __bf16 bf16x8 __attribute__((ext_vector_type(8)));
typedef float  f32x4  __attribute__((ext_vector_type(4)));
typedef float  f32x16 __attribute__((ext_vector_type(16)));

__device__ __forceinline__ ushort f2bf(float f) {
    unsigned b = __float_as_uint(f);
    return (ushort)((b + 0x7FFFu + ((b >> 16) & 1u)) >> 16);   // RNE, finite data
}
__device__ __forceinline__ float bf2f(ushort u) {
    return __uint_as_float((unsigned)u << 16);
}

__device__ __forceinline__ unsigned cvtpk(float lo, float hi) {
    unsigned r;
    asm("v_cvt_pk_bf16_f32 %0, %1, %2" : "=v"(r) : "v"(lo), "v"(hi));
    return r;
}

// v_permlane32_swap_b32: a' = [a.lo | b.lo(from lane-32)], b' = [a.hi | b.hi]
__device__ __forceinline__ void plswap(unsigned &a, unsigned &b) {
    asm("v_permlane32_swap_b32 %0, %1" : "+v"(a), "+v"(b));
}

#define GLD16(src, dst) __builtin_amdgcn_global_load_lds(                      \
    (const __attribute__((address_space(1))) unsigned int*)(src),              \
    (__attribute__((address_space(3))) unsigned int*)(dst), 16, 0, 0)

// swizzled LDS element index for [row][col] tiles, 64-elem (128B) rows
#define SW(row, col) ((row)*64 + ((col) ^ (((row)&7)<<3)))

// XCD-aware block swizzle (bijective: nwg % 8 == 0 for all our grids)
__device__ __forceinline__ int2 xcd_swz(int gx, int gy) {
    const int nwg = gx * gy;
    int id = blockIdx.y * gx + blockIdx.x;
    id = (id & 7) * (nwg >> 3) + (id >> 3);
    return make_int2(id % gx, id / gx);
}

// ---------------------------------------------------------------------------
// Fused prep: [0,2048) cast x; [2048,4096) transpose w_t; [4096,5120)
// transpose w_o; [5120,5124) mask prefix scan -> cpos/spos/nvalid.
// ---------------------------------------------------------------------------
__global__ __launch_bounds__(256)
void prep_all(const float* __restrict__ x, const float* __restrict__ w_t,
              const float* __restrict__ w_o, const int* __restrict__ mask,
              ushort* __restrict__ xbf, ushort* __restrict__ wtT,
              ushort* __restrict__ woT, int* __restrict__ cpos,
              int* __restrict__ spos, int* __restrict__ nvalid)
{
    __shared__ float tile[32][33];
    const int bid = blockIdx.x;
    if (bid >= 5120) {
        // mask prefix scan for batch b
        const int b = bid - 5120;
        int* part = (int*)tile;
        const int t = threadIdx.x;
        int4 m = *(const int4*)(mask + b*SEQ + t*4);
        const int v0 = (m.x != 0), v1 = (m.y != 0);
        const int v2 = (m.z != 0), v3 = (m.w != 0);
        const int mine = v0 + v1 + v2 + v3;
        part[t] = mine;
        __syncthreads();
        for (int off = 1; off < 256; off <<= 1) {
            int y = (t >= off) ? part[t - off] : 0;
            __syncthreads();
            part[t] += y;
            __syncthreads();
        }
        const int ex = part[t] - mine;          // exclusive prefix
        int4 o;
        o.x = v0 ? ex : -1;
        o.y = v1 ? ex + v0 : -1;
        o.z = v2 ? ex + v0 + v1 : -1;
        o.w = v3 ? ex + v0 + v1 + v2 : -1;
        *(int4*)(cpos + b*SEQ + t*4) = o;
        if (v0) spos[b*SEQ + o.x] = t*4 + 0;
        if (v1) spos[b*SEQ + o.y] = t*4 + 1;
        if (v2) spos[b*SEQ + o.z] = t*4 + 2;
        if (v3) spos[b*SEQ + o.w] = t*4 + 3;
        if (t == 255) nvalid[b] = part[255];
        return;
    }
    if (bid < 2048) {
        const size_t i = ((size_t)bid * 256 + threadIdx.x) * 8;
        float4 v0 = *(const float4*)(x + i);
        float4 v1 = *(const float4*)(x + i + 4);
        ushort o[8] = {f2bf(v0.x), f2bf(v0.y), f2bf(v0.z), f2bf(v0.w),
                       f2bf(v1.x), f2bf(v1.y), f2bf(v1.z), f2bf(v1.w)};
        *(uint4*)(xbf + i) = *(uint4*)o;
        return;
    }
    const float* W; ushort* WT; int K, N, bn, bk;
    if (bid < 4096) {
        W = w_t; WT = wtT; K = DIMX; N = TW;
        const int t = bid - 2048;               // 64 x 32 tiles
        bn = (t & 63) * 32; bk = (t >> 6) * 32;
    } else {
        W = w_o; WT = woT; K = DIMX; N = DIMX;
        const int t = bid - 4096;               // 32 x 32 tiles
        bn = (t & 31) * 32; bk = (t >> 5) * 32;
    }
    const int tx = threadIdx.x & 31;
    const int ty = threadIdx.x >> 5;
    #pragma unroll
    for (int i = ty; i < 32; i += 8)
        tile[i][tx] = W[(size_t)(bk + i) * N + bn + tx];
    __syncthreads();
    #pragma unroll
    for (int i = ty; i < 32; i += 8)
        WT[(size_t)(bn + i) * K + bk + tx] = f2bf(tile[tx][i]);
}

// ---------------------------------------------------------------------------
// Shared GEMM body: 128x128 tile, BK=64, DOUBLE-BUFFERED swizzled LDS,
// 2-phase counted-vmcnt pipeline.
// ---------------------------------------------------------------------------
#define GEMM_PROLOGUE(Aptr, Bptr, Kdim)                                        \
    __shared__ __align__(16) ushort lA[2 * 128 * 64];                          \
    __shared__ __align__(16) ushort lB[2 * 128 * 64];                          \
    const int tid  = threadIdx.x;                                              \
    const int lane = tid & 63;                                                 \
    const int wave = tid >> 6;                                                 \
    const int wr   = wave >> 1;                                                \
    const int wc   = wave & 1;                                                 \
    const int rsub = lane >> 3;                   /* row within 8-chunk */     \
    const int scol = ((lane & 7) * 8) ^ ((rsub & 7) << 3);                     \
    const ushort* aP = (Aptr) + (size_t)(bm + wave*32 + rsub) * (Kdim) + scol; \
    const ushort* bP = (Bptr) + (size_t)(bn + wave*32 + rsub) * (Kdim) + scol; \
    ushort* lAw = lA + wave * 2048;                                            \
    ushort* lBw = lB + wave * 2048;                                            \
    const int fr = lane & 15;                                                  \
    const int l4 = lane >> 4;                                                  \
    f32x4 acc[4][4] = {};

#define GSTAGE(buf, k0, Kdim)                                                  \
    do {                                                                       \
        _Pragma("unroll")                                                      \
        for (int c = 0; c < 4; ++c) {                                          \
            GLD16(aP + (size_t)(c*8) * (Kdim) + (k0), lAw + (buf)*8192 + c*512);\
            GLD16(bP + (size_t)(c*8) * (Kdim) + (k0), lBw + (buf)*8192 + c*512);\
        }                                                                      \
    } while (0)

#define GEMM_KLOOP(Kdim)                                                       \
    GSTAGE(0, 0, Kdim);                                                        \
    for (int t = 0; t < (Kdim)/64; ++t) {                                      \
        const int cur = t & 1;                                                 \
        if (t < (Kdim)/64 - 1) {                                               \
            GSTAGE(cur ^ 1, (t + 1) * 64, Kdim);                               \
            asm volatile("s_waitcnt vmcnt(8)" ::: "memory");                   \
        } else {                                                               \
            asm volatile("s_waitcnt vmcnt(0)" ::: "memory");                   \
        }                                                                      \
        __builtin_amdgcn_s_barrier();            /* tile t visible to all */   \
        _Pragma("unroll")                                                      \
        for (int ks = 0; ks < 2; ++ks) {                                       \
            bf16x8 af[4], bfr[4];                                              \
            _Pragma("unroll")                                                  \
            for (int m = 0; m < 4; ++m)                                        \
                af[m] = *(const bf16x8*)&lA[cur*8192 +                         \
                    SW(wr*64 + m*16 + fr, ks*32 + l4*8)];                      \
            _Pragma("unroll")                                                  \
            for (int n = 0; n < 4; ++n)                                        \
                bfr[n] = *(const bf16x8*)&lB[cur*8192 +                        \
                    SW(wc*64 + n*16 + fr, ks*32 + l4*8)];                      \
            _Pragma("unroll")                                                  \
            for (int m = 0; m < 4; ++m)                                        \
                _Pragma("unroll")                                              \
                for (int n = 0; n < 4; ++n)                                    \
                    acc[m][n] = __builtin_amdgcn_mfma_f32_16x16x32_bf16(       \
                        af[m], bfr[n], acc[m][n], 0, 0, 0);                    \
        }                                                                      \
        asm volatile("s_waitcnt lgkmcnt(0)" ::: "memory");                     \
        __builtin_amdgcn_s_barrier();            /* reads done before reuse */ \
    }

// ---------------------------------------------------------------------------
// GEMM1 with split epilogue: cols [0,1024) -> t1b bf16 (q,k);
// cols [1024,2048) -> FULL transposed bf16 Vt[bh][vd][s] (vectorized).
// ---------------------------------------------------------------------------
__global__ __launch_bounds__(256, 2)
void gemm_qkv(const ushort* __restrict__ A, const ushort* __restrict__ BT,
              ushort* __restrict__ t1b, ushort* __restrict__ Vt)
{
    const int2 bij = xcd_swz(TW/128, NPOS/128);
    const int bm = bij.y * 128;
    const int bn = bij.x * 128;
    GEMM_PROLOGUE(A, BT, DIMX)
    GEMM_KLOOP(DIMX)

    const int orow = l4 * 4;
    if (bn < 1024) {
        #pragma unroll
        for (int m = 0; m < 4; ++m)
            #pragma unroll
            for (int n = 0; n < 4; ++n) {
                ushort* dst = t1b + (size_t)(bm + wr * 64 + m * 16 + orow) * 1024
                                  + bn + wc * 64 + n * 16 + fr;
                #pragma unroll
                for (int q = 0; q < 4; ++q)
                    dst[(size_t)q * 1024] = f2bf(acc[m][n][q]);
            }
    } else {
        #pragma unroll
        for (int m = 0; m < 4; ++m)
            #pragma unroll
            for (int n = 0; n < 4; ++n) {
                const int row0 = bm + wr * 64 + m * 16 + orow;   // 4-aligned s
                const int cv   = bn + wc * 64 + n * 16 + fr - 1024;
                const int hh = cv >> 7, vd = cv & 127;
                const int bb = row0 >> 10, ss = row0 & 1023;
                ushort o4[4];
                #pragma unroll
                for (int q = 0; q < 4; ++q) o4[q] = f2bf(acc[m][n][q]);
                *(ushort4*)&Vt[((size_t)(bb*NH + hh)*VDD + vd)*SEQ + ss] =
                    *(ushort4*)o4;
            }
    }
}

// ---------------------------------------------------------------------------
// Compact V: Vc[bh][vd][ci] = Vt[bh][vd][spos[ci]]. spos staged in LDS;
// writes fully coalesced, reads L2-resident gathers. Grid (32, 8).
// ---------------------------------------------------------------------------
__global__ __launch_bounds__(256)
void compact_v(const ushort* __restrict__ Vt, const int* __restrict__ spos,
               const int* __restrict__ nvalid, ushort* __restrict__ Vc)
{
    const int bh = blockIdx.x;          // 0..31
    const int vg = blockIdx.y;          // 0..7 (16 vd rows each)
    const int b  = bh >> 3;
    const int tid = threadIdx.x;
    const int nv = nvalid[b];

    __shared__ int sps[SEQ];
    for (int i = tid; i < nv; i += 256) sps[i] = spos[b*SEQ + i];
    __syncthreads();

    const ushort* src = Vt + (size_t)bh*VDD*SEQ;
    ushort* dst = Vc + (size_t)bh*VDD*SEQ;
    #pragma unroll
    for (int v = 0; v < 16; ++v) {
        const int vd = vg*16 + v;
        const ushort* srow = src + (size_t)vd*SEQ;
        ushort* drow = dst + (size_t)vd*SEQ;
        for (int ci = tid; ci < nv; ci += 256)
            drow[ci] = srow[sps[ci]];
    }
}

// ---------------------------------------------------------------------------
// GEMM2 re-tiled 64(M)x128(N), BK=64 (r15-verified): 512 blocks, 2/CU.
// ---------------------------------------------------------------------------
__global__ __launch_bounds__(256, 2)
void gemm_bf16_mfma(const ushort* __restrict__ A, const ushort* __restrict__ BT,
                    float* __restrict__ C)
{
    __shared__ __align__(16) ushort lA[2 * 64 * 64];     // 16KB
    __shared__ __align__(16) ushort lB[2 * 128 * 64];    // 32KB

    const int2 bij = xcd_swz(DIMX/128, NPOS/64);         // gx=8, gy=64
    const int bm = bij.y * 64;
    const int bn = bij.x * 128;
    const int tid  = threadIdx.x;
    const int lane = tid & 63;
    const int wave = tid >> 6;
    const int wr   = wave >> 1;          // 0..1 (32-row half)
    const int wc   = wave & 1;           // 0..1 (64-col half)
    const int rsub = lane >> 3;
    const int scol = ((lane & 7) * 8) ^ ((rsub & 7) << 3);
    const ushort* aP = A  + (size_t)(bm + wave*16 + rsub) * DIMX + scol;
    const ushort* bP = BT + (size_t)(bn + wave*32 + rsub) * DIMX + scol;
    ushort* lAw = lA + wave * 1024;      // 16 rows x 64
    ushort* lBw = lB + wave * 2048;      // 32 rows x 64
    const int fr = lane & 15;
    const int l4 = lane >> 4;
    f32x4 acc[2][4] = {};

#define GSTAGE2(buf, k0) do {                                                  \
    _Pragma("unroll")                                                          \
    for (int c = 0; c < 2; ++c)                                                \
        GLD16(aP + (size_t)(c*8) * DIMX + (k0), lAw + (buf)*4096 + c*512);     \
    _Pragma("unroll")                                                          \
    for (int c = 0; c < 4; ++c)                                                \
        GLD16(bP + (size_t)(c*8) * DIMX + (k0), lBw + (buf)*8192 + c*512);     \
} while (0)

    GSTAGE2(0, 0);
    for (int t = 0; t < 16; ++t) {
        const int cur = t & 1;
        if (t < 15) {
            GSTAGE2(cur ^ 1, (t + 1) * 64);
            asm volatile("s_waitcnt vmcnt(6)" ::: "memory");   // tile t landed
        } else {
            asm volatile("s_waitcnt vmcnt(0)" ::: "memory");
        }
        __builtin_amdgcn_s_barrier();
        #pragma unroll
        for (int ks = 0; ks < 2; ++ks) {
            bf16x8 af[2], bfr[4];
            #pragma unroll
            for (int m = 0; m < 2; ++m)
                af[m] = *(const bf16x8*)&lA[cur*4096 +
                    SW(wr*32 + m*16 + fr, ks*32 + l4*8)];
            #pragma unroll
            for (int n = 0; n < 4; ++n)
                bfr[n] = *(const bf16x8*)&lB[cur*8192 +
                    SW(wc*64 + n*16 + fr, ks*32 + l4*8)];
            #pragma unroll
            for (int m = 0; m < 2; ++m)
                #pragma unroll
                for (int n = 0; n < 4; ++n)
                    acc[m][n] = __builtin_amdgcn_mfma_f32_16x16x32_bf16(
                        af[m], bfr[n], acc[m][n], 0, 0, 0);
        }
        asm volatile("s_waitcnt lgkmcnt(0)" ::: "memory");
        __builtin_amdgcn_s_barrier();
    }
#undef GSTAGE2

    const int orow = l4 * 4;
    #pragma unroll
    for (int m = 0; m < 2; ++m)
        #pragma unroll
        for (int n = 0; n < 4; ++n) {
            float* dst = C + (size_t)(bm + wr*32 + m*16 + orow) * DIMX
                           + bn + wc*64 + n*16 + fr;
            #pragma unroll
            for (int q = 0; q < 4; ++q)
                dst[(size_t)q * DIMX] = acc[m][n][q];
        }
}

// ---------------------------------------------------------------------------
// Fused masked rotation + bf16 pack, VECTORIZED LDS version (r14-verified).
// ---------------------------------------------------------------------------
__global__ __launch_bounds__(256)
void rotate_pack_qk(const ushort* __restrict__ t1b, const int* __restrict__ mask,
                    const float* __restrict__ rot, ushort* __restrict__ Qb,
                    ushort* __restrict__ Kc, const int* __restrict__ cpos)
{
    const int p   = blockIdx.x;
    const int tid = threadIdx.x;
    const int b = p >> 10, s = p & 1023;
    const bool rotated = (mask[p] != 0);   // block-uniform
    const int cp = cpos[p];                // >=0 iff rotated

    if (!rotated) {
        if (tid < 128) {
            const int h  = tid >> 4;
            const int i4 = (tid & 15) * 4;
            ushort4 q4 = *(const ushort4*)(t1b + (size_t)p*1024 + tid*4);
            ushort o[4];
            o[0] = f2bf(bf2f(q4.x) * SCALE);
            o[1] = f2bf(bf2f(q4.y) * SCALE);
            o[2] = f2bf(bf2f(q4.z) * SCALE);
            o[3] = f2bf(bf2f(q4.w) * SCALE);
            *(ushort4*)&Qb[((size_t)(b*NH + h)*SEQ + s)*HD + i4] = *(ushort4*)o;
        }
        return;
    }

    __shared__ __align__(16) float Rsw [64*64];   // R,  rows XOR-swizzled
    __shared__ __align__(16) float RTsw[64*64];   // R^T, rows XOR-swizzled

    {
        const int r  = tid >> 2;
        const int c0 = (tid & 3) * 16;
        const float* Rg = rot + (size_t)p * 4096 + (size_t)r * 64 + c0;
        #pragma unroll
        for (int u = 0; u < 4; ++u) {
            float4 v = *(const float4*)(Rg + 4*u);
            const int c4 = c0 + 4*u;
            *(float4*)&Rsw[r*64 + (c4 ^ ((r & 15) << 2))] = v;
            RTsw[(c4+0)*64 + (r ^ (((c4+0) & 15) << 2))] = v.x;
            RTsw[(c4+1)*64 + (r ^ (((c4+1) & 15) << 2))] = v.y;
            RTsw[(c4+2)*64 + (r ^ (((c4+2) & 15) << 2))] = v.z;
            RTsw[(c4+3)*64 + (r ^ (((c4+3) & 15) << 2))] = v.w;
        }
    }
    __syncthreads();

    const int i  = tid & 63;
    const int h0 = __builtin_amdgcn_readfirstlane(tid >> 6);   // wave-uniform
    const ushort* qg0 = t1b + (size_t)p*1024 + h0*64;
    const ushort* kg0 = t1b + (size_t)p*1024 + QKD + h0*64;
    const ushort* qg1 = qg0 + 4*64;
    const ushort* kg1 = kg0 + 4*64;

    float aq0 = 0.f, ak0 = 0.f, aq1 = 0.f, ak1 = 0.f;
    const int swk = (i & 15) << 2;
    #pragma unroll
    for (int jc = 0; jc < 16; ++jc) {
        const int j4 = jc * 4;
        const float4 Rv = *(const float4*)&Rsw [i*64 + (j4 ^ swk)];
        const float4 Tv = *(const float4*)&RTsw[i*64 + (j4 ^ swk)];
        const ushort4 qa = *(const ushort4*)(qg0 + j4);
        const ushort4 ka = *(const ushort4*)(kg0 + j4);
        const ushort4 qb = *(const ushort4*)(qg1 + j4);
        const ushort4 kb = *(const ushort4*)(kg1 + j4);
        aq0 = fmaf(Rv.x, bf2f(qa.x), aq0); aq0 = fmaf(Rv.y, bf2f(qa.y), aq0);
        aq0 = fmaf(Rv.z, bf2f(qa.z), aq0); aq0 = fmaf(Rv.w, bf2f(qa.w), aq0);
        ak0 = fmaf(Tv.x, bf2f(ka.x), ak0); ak0 = fmaf(Tv.y, bf2f(ka.y), ak0);
        ak0 = fmaf(Tv.z, bf2f(ka.z), ak0); ak0 = fmaf(Tv.w, bf2f(ka.w), ak0);
        aq1 = fmaf(Rv.x, bf2f(qb.x), aq1); aq1 = fmaf(Rv.y, bf2f(qb.y), aq1);
        aq1 = fmaf(Rv.z, bf2f(qb.z), aq1); aq1 = fmaf(Rv.w, bf2f(qb.w), aq1);
        ak1 = fmaf(Tv.x, bf2f(kb.x), ak1); ak1 = fmaf(Tv.y, bf2f(kb.y), ak1);
        ak1 = fmaf(Tv.z, bf2f(kb.z), ak1); ak1 = fmaf(Tv.w, bf2f(kb.w), ak1);
    }

    Qb[((size_t)(b*NH + h0    )*SEQ + s )*HD + i] = f2bf(aq0 * SCALE);
    Kc[((size_t)(b*NH + h0    )*SEQ + cp)*HD + i] = f2bf(ak0);
    Qb[((size_t)(b*NH + h0 + 4)*SEQ + s )*HD + i] = f2bf(aq1 * SCALE);
    Kc[((size_t)(b*NH + h0 + 4)*SEQ + cp)*HD + i] = f2bf(ak1);
}

// ---------------------------------------------------------------------------
// MFMA Taylor attention on COMPACTED keys (r13-verified): 32x32x16,
// in-register P, split-K wave pairs, counted vmcnt + raw s_barrier.
// ---------------------------------------------------------------------------
__global__ __launch_bounds__(256, 2)
void taylor_attn_mfma(const ushort* __restrict__ Qb, const ushort* __restrict__ Kc,
                      const ushort* __restrict__ Vc, const int* __restrict__ nvalid,
                      ushort* __restrict__ attn)
{
    const int bh  = blockIdx.x;        // 0..31
    const int qt  = blockIdx.y;        // 0..15 (64 q-rows each)
    const int b   = bh >> 3, h = bh & 7;
    const int tid = threadIdx.x;
    const int lane = tid & 63;
    const int wave = tid >> 6;
    const int kh  = wave >> 1;         // key-half
    const int qg  = wave & 1;          // q-group (32 rows)
    const int l31 = lane & 31;
    const int g   = lane >> 5;         // 0..1

    __shared__ __align__(16) ushort smem[32768];
    __shared__ float dpart[64];
    __shared__ float dinv2[64];

    ushort* Ksp = smem + kh * 8192;            // my pair's K dbuf [2][4096]
    ushort* Vsp = smem + 16384 + kh * 8192;    // my pair's V [8192]
    float*  comb = (float*)smem;               // epilogue partial-O (32KB)

    const int nv = nvalid[b];                  // valid keys this batch
    const int T  = (nv + 63) >> 6;             // 64-key tiles
    const int Th = (T + 1) >> 1;               // tiles per key-half

    const ushort* qrow = Qb + ((size_t)bh*SEQ + qt*64 + qg*32 + l31) * HD + g*8;
    bf16x8 qf[4];
    #pragma unroll
    for (int ds = 0; ds < 4; ++ds) qf[ds] = *(const bf16x8*)(qrow + ds*16);

    const int sub  = lane >> 3;
    const int scol = ((lane & 7) * 8) ^ (sub << 3);
    const ushort* Kbase = Kc + (size_t)bh*SEQ*HD;
    const ushort* Vbase = Vc + (size_t)bh*VDD*SEQ;

#define ISSUE_K(buf, ktn) do {                                                 \
    _Pragma("unroll")                                                          \
    for (int i_ = 0; i_ < 4; ++i_)                                             \
        GLD16(Kbase + ((size_t)(ktn)*64 + 8*(qg*4+i_) + sub)*HD + scol,        \
              Ksp + (buf)*4096 + (qg*4+i_)*512);                               \
} while (0)
#define ISSUE_V(ktn) do {                                                      \
    _Pragma("unroll")                                                          \
    for (int i_ = 0; i_ < 8; ++i_)                                             \
        GLD16(Vbase + (size_t)(8*(qg*8+i_) + sub)*SEQ + (ktn)*64 + scol,       \
              Vsp + (qg*8+i_)*512);                                            \
} while (0)

    f32x16 acc[4] = {};
    float dacc = 0.f;

    asm volatile("s_waitcnt vmcnt(0)" ::: "memory");   // qf retired: exact counts
    ISSUE_K(0, kh*Th);

    for (int it = 0; it < Th; ++it) {
        const int kt = kh*Th + it;
        const int cb = it & 1;
        ISSUE_V(kt);                                   // +8 -> 12
        if (it < Th - 1) {
            ISSUE_K(cb ^ 1, kt + 1);                   // +4 -> 16
            asm volatile("s_waitcnt vmcnt(12)" ::: "memory");  // K(it) landed
        } else {
            asm volatile("s_waitcnt vmcnt(8)"  ::: "memory");  // last K landed
        }
        __builtin_amdgcn_s_barrier();

        f32x16 sf0 = {}, sf1 = {};
        __builtin_amdgcn_s_setprio(1);
        #pragma unroll
        for (int ds = 0; ds < 4; ++ds) {
            const int dc = ds*16 + g*8;
            bf16x8 kf0 = *(const bf16x8*)&Ksp[cb*4096 + SW(l31, dc)];
            bf16x8 kf1 = *(const bf16x8*)&Ksp[cb*4096 + SW(32 + l31, dc)];
            sf0 = __builtin_amdgcn_mfma_f32_32x32x16_bf16(kf0, qf[ds], sf0, 0, 0, 0);
            sf1 = __builtin_amdgcn_mfma_f32_32x32x16_bf16(kf1, qf[ds], sf1, 0, 0, 0);
        }
        __builtin_amdgcn_s_setprio(0);

        // ---- transform + pack; validity mask = (key index < nv) inline ----
        const int kb0 = kt*64 + 4*g;
        unsigned w0[8], w1[8];
        float dadd = 0.f;
        #pragma unroll
        for (int rr = 0; rr < 4; ++rr) {
            const int ka = kb0 + 8*rr;          // sf0 keys ka+0..3
            const float ma0 = (ka + 0 < nv) ? 1.f : 0.f;
            const float ma1 = (ka + 1 < nv) ? 1.f : 0.f;
            const float ma2 = (ka + 2 < nv) ? 1.f : 0.f;
            const float ma3 = (ka + 3 < nv) ? 1.f : 0.f;
            const float mb0 = (ka + 32 < nv) ? 1.f : 0.f;
            const float mb1 = (ka + 33 < nv) ? 1.f : 0.f;
            const float mb2 = (ka + 34 < nv) ? 1.f : 0.f;
            const float mb3 = (ka + 35 < nv) ? 1.f : 0.f;
            float s0 = sf0[rr*4+0], s1 = sf0[rr*4+1];
            float s2 = sf0[rr*4+2], s3 = sf0[rr*4+3];
            float c0 = fmaf(fmaf(0.5f*s0, s0, s0), ma0, ma0);
            float c1 = fmaf(fmaf(0.5f*s1, s1, s1), ma1, ma1);
            float c2 = fmaf(fmaf(0.5f*s2, s2, s2), ma2, ma2);
            float c3 = fmaf(fmaf(0.5f*s3, s3, s3), ma3, ma3);
            float t0 = sf1[rr*4+0], t1 = sf1[rr*4+1];
            float t2 = sf1[rr*4+2], t3 = sf1[rr*4+3];
            float d0 = fmaf(fmaf(0.5f*t0, t0, t0), mb0, mb0);
            float d1 = fmaf(fmaf(0.5f*t1, t1, t1), mb1, mb1);
            float d2 = fmaf(fmaf(0.5f*t2, t2, t2), mb2, mb2);
            float d3 = fmaf(fmaf(0.5f*t3, t3, t3), mb3, mb3);
            dadd += ((c0+c1)+(c2+c3)) + ((d0+d1)+(d2+d3));
            w0[rr*2+0] = cvtpk(c0, c1);
            w0[rr*2+1] = cvtpk(c2, c3);
            w1[rr*2+0] = cvtpk(d0, d1);
            w1[rr*2+1] = cvtpk(d2, d3);
        }
        dacc += dadd;
        plswap(w0[0], w0[2]); plswap(w0[1], w0[3]);
        plswap(w0[4], w0[6]); plswap(w0[5], w0[7]);
        plswap(w1[0], w1[2]); plswap(w1[1], w1[3]);
        plswap(w1[4], w1[6]); plswap(w1[5], w1[7]);

        if (it < Th - 1) asm volatile("s_waitcnt vmcnt(4)" ::: "memory");
        else             asm volatile("s_waitcnt vmcnt(0)" ::: "memory");
        __builtin_amdgcn_s_barrier();

        __builtin_amdgcn_s_setprio(1);
        #pragma unroll
        for (int kq = 0; kq < 4; ++kq) {
            union { unsigned u[4]; bf16x8 v; } pu;
            if (kq == 0)      { pu.u[0]=w0[0]; pu.u[1]=w0[1]; pu.u[2]=w0[2]; pu.u[3]=w0[3]; }
            else if (kq == 1) { pu.u[0]=w0[4]; pu.u[1]=w0[5]; pu.u[2]=w0[6]; pu.u[3]=w0[7]; }
            else if (kq == 2) { pu.u[0]=w1[0]; pu.u[1]=w1[1]; pu.u[2]=w1[2]; pu.u[3]=w1[3]; }
            else              { pu.u[0]=w1[4]; pu.u[1]=w1[5]; pu.u[2]=w1[6]; pu.u[3]=w1[7]; }
            const int kcol = kq*16 + g*8;
            acc[0] = __builtin_amdgcn_mfma_f32_32x32x16_bf16(
                pu.v, *(const bf16x8*)&Vsp[SW(      l31, kcol)], acc[0], 0, 0, 0);
            acc[1] = __builtin_amdgcn_mfma_f32_32x32x16_bf16(
                pu.v, *(const bf16x8*)&Vsp[SW( 32 + l31, kcol)], acc[1], 0, 0, 0);
            acc[2] = __builtin_amdgcn_mfma_f32_32x32x16_bf16(
                pu.v, *(const bf16x8*)&Vsp[SW( 64 + l31, kcol)], acc[2], 0, 0, 0);
            acc[3] = __builtin_amdgcn_mfma_f32_32x32x16_bf16(
                pu.v, *(const bf16x8*)&Vsp[SW( 96 + l31, kcol)], acc[3], 0, 0, 0);
        }
        __builtin_amdgcn_s_setprio(0);
        __builtin_amdgcn_s_barrier();   // reads done; safe to overwrite / reuse
    }
#undef ISSUE_K
#undef ISSUE_V

    const float dhalf = dacc + __shfl_xor(dacc, 32);

    if (kh == 1) {
        float* cbp = comb + qg * 4096;                 // [vd 128][q 32] f32
        #pragma unroll
        for (int vb = 0; vb < 4; ++vb)
            #pragma unroll
            for (int rr = 0; rr < 4; ++rr) {
                float4 v = make_float4(acc[vb][rr*4+0], acc[vb][rr*4+1],
                                       acc[vb][rr*4+2], acc[vb][rr*4+3]);
                *(float4*)&cbp[(vb*32 + l31)*32 + 4*g + 8*rr] = v;
            }
        if (lane < 32) dpart[qg*32 + l31] = dhalf;
    }
    __syncthreads();
    if (kh == 0) {
        float* cbp = comb + qg * 4096;
        const float dtot = dhalf + dpart[qg*32 + l31];
        if (lane < 32) dinv2[qg*32 + l31] = 1.f / fmaxf(dtot, 1e-6f);
        #pragma unroll
        for (int vb = 0; vb < 4; ++vb)
            #pragma unroll
            for (int rr = 0; rr < 4; ++rr) {
                float4 v = *(const float4*)&cbp[(vb*32 + l31)*32 + 4*g + 8*rr];
                acc[vb][rr*4+0] += v.x; acc[vb][rr*4+1] += v.y;
                acc[vb][rr*4+2] += v.z; acc[vb][rr*4+3] += v.w;
            }
        float inv[16];
        #pragma unroll
        for (int rr = 0; rr < 4; ++rr) {
            float4 iv = *(const float4*)&dinv2[qg*32 + 8*rr + 4*g];
            inv[rr*4+0] = iv.x; inv[rr*4+1] = iv.y;
            inv[rr*4+2] = iv.z; inv[rr*4+3] = iv.w;
        }
        ushort* obase = attn + ((size_t)(b*SEQ + qt*64 + qg*32)) * DIMX
                      + h*VDD + l31;
        #pragma unroll
        for (int vb = 0; vb < 4; ++vb)
            #pragma unroll
            for (int rr = 0; rr < 4; ++rr)
                #pragma unroll
                for (int j = 0; j < 4; ++j) {
                    const int q = 4*g + 8*rr + j;
                    obase[(size_t)q*DIMX + vb*32] = f2bf(acc[vb][rr*4+j] * inv[rr*4+j]);
                }
    }
}

// ---------------------------------------------------------------------------
extern "C" void kernel_launch(void* const* d_in, const int* in_sizes, int n_in,
                              void* d_out, int out_size, void* d_ws, size_t ws_size,
                              hipStream_t stream)
{
    const float* x    = (const float*)d_in[0];
    const int*   mask = (const int*)d_in[1];
    const float* rot  = (const float*)d_in[2];
    const float* w_t  = (const float*)d_in[3];
    const float* w_o  = (const float*)d_in[4];
    float* out = (float*)d_out;

    // workspace (~46 MB + 32KB):
    // t1b 8 | xbf/attnbf 8 | wtT 4 | woT 2 | Qb 4 | Kc 4 | Vt 8 | Vc 8
    // | cpos 16KB | spos 16KB | nvalid
    ushort* t1b    = (ushort*)d_ws;
    ushort* xbf    = t1b + (size_t)NPOS * 1024;
    ushort* attnbf = xbf;                            // xbf dead after gemm_qkv
    ushort* wtT    = xbf + (size_t)NPOS * DIMX;
    ushort* woT    = wtT + (size_t)TW * DIMX;
    ushort* Qb     = woT + (size_t)DIMX * DIMX;
    ushort* Kc     = Qb  + (size_t)BATCH * NH * SEQ * HD;
    ushort* Vt     = Kc  + (size_t)BATCH * NH * SEQ * HD;
    ushort* Vc     = Vt  + (size_t)BATCH * NH * VDD * SEQ;
    int*    cpos   = (int*)(Vc + (size_t)BATCH * NH * VDD * SEQ);
    int*    spos   = cpos + NPOS;
    int*    nvalid = spos + NPOS;

    // 0) fused prep: casts + weight transposes + mask prefix scan (cpos+spos)
    prep_all<<<5124, 256, 0, stream>>>(x, w_t, w_o, mask, xbf, wtT, woT,
                                       cpos, spos, nvalid);

    // 1) qkv projection: q,k -> t1b bf16; v -> FULL Vt bf16 (vectorized)
    gemm_qkv<<<dim3(TW/128, NPOS/128), 256, 0, stream>>>(xbf, wtT, t1b, Vt);
    // 2) compact V: Vc[vd][ci] = Vt[vd][spos[ci]] (coalesced writes)
    compact_v<<<dim3(BATCH*NH, 8), 256, 0, stream>>>(Vt, spos, nvalid, Vc);
    // 3) fused masked rotation (vectorized R/R^T LDS) -> Qb, Kc
    rotate_pack_qk<<<NPOS, 256, 0, stream>>>(t1b, mask, rot, Qb, Kc, cpos);
    // 4) fused MFMA Taylor attention on compacted keys -> attnbf
    taylor_attn_mfma<<<dim3(BATCH*NH, SEQ/64), 256, 0, stream>>>(Qb, Kc, Vc,
                                                                 nvalid, attnbf);
    // 5) out = attn @ w_o  (64x128 tiles, 512 blocks)
    gemm_bf16_mfma<<<dim3(DIMX/128, NPOS/64), 256, 0, stream>>>(attnbf, woT, out);
}

// Round 17
// 89.380 us; speedup vs baseline: 1.0966x; 1.0966x over previous
//
#include <hip/hip_runtime.h>
#include <cstdint>
#include <cstddef>

#define DIMX  1024
#define NH    8
#define HD    64
#define QKD   512            // NH*HD
#define VDD   128            // DIMX/NH
#define BATCH 4
#define SEQ   1024
#define NPOS  (BATCH*SEQ)    // 4096
#define TW    (2*QKD + DIMX) // 2048
#define SCALE 0.125f         // HD^-0.5 (folded into Qb at pack time)

typedef __bf16 bf16x8 __attribute__((ext_vector_type(8)));
typedef float  f32x4  __attribute__((ext_vector_type(4)));
typedef float  f32x16 __attribute__((ext_vector_type(16)));

__device__ __forceinline__ ushort f2bf(float f) {
    unsigned b = __float_as_uint(f);
    return (ushort)((b + 0x7FFFu + ((b >> 16) & 1u)) >> 16);   // RNE, finite data
}
__device__ __forceinline__ float bf2f(ushort u) {
    return __uint_as_float((unsigned)u << 16);
}

__device__ __forceinline__ unsigned cvtpk(float lo, float hi) {
    unsigned r;
    asm("v_cvt_pk_bf16_f32 %0, %1, %2" : "=v"(r) : "v"(lo), "v"(hi));
    return r;
}

// v_permlane32_swap_b32: a' = [a.lo | b.lo(from lane-32)], b' = [a.hi | b.hi]
__device__ __forceinline__ void plswap(unsigned &a, unsigned &b) {
    asm("v_permlane32_swap_b32 %0, %1" : "+v"(a), "+v"(b));
}

#define GLD16(src, dst) __builtin_amdgcn_global_load_lds(                      \
    (const __attribute__((address_space(1))) unsigned int*)(src),              \
    (__attribute__((address_space(3))) unsigned int*)(dst), 16, 0, 0)

// swizzled LDS element index for [row][col] tiles, 64-elem (128B) rows
#define SW(row, col) ((row)*64 + ((col) ^ (((row)&7)<<3)))

// XCD-aware block swizzle (bijective: nwg % 8 == 0 for all our grids)
__device__ __forceinline__ int2 xcd_swz(int gx, int gy) {
    const int nwg = gx * gy;
    int id = blockIdx.y * gx + blockIdx.x;
    id = (id & 7) * (nwg >> 3) + (id >> 3);
    return make_int2(id % gx, id / gx);
}

// ---------------------------------------------------------------------------
// Fused prep: [0,2048) cast x; [2048,4096) transpose w_t; [4096,5120)
// transpose w_o; [5120,5124) per-batch mask prefix scan -> cpos/nvalid.
// ---------------------------------------------------------------------------
__global__ __launch_bounds__(256)
void prep_all(const float* __restrict__ x, const float* __restrict__ w_t,
              const float* __restrict__ w_o, const int* __restrict__ mask,
              ushort* __restrict__ xbf, ushort* __restrict__ wtT,
              ushort* __restrict__ woT, int* __restrict__ cpos,
              int* __restrict__ nvalid)
{
    __shared__ float tile[32][33];
    const int bid = blockIdx.x;
    if (bid >= 5120) {
        // mask prefix scan for batch b
        const int b = bid - 5120;
        int* part = (int*)tile;
        const int t = threadIdx.x;
        int4 m = *(const int4*)(mask + b*SEQ + t*4);
        const int v0 = (m.x != 0), v1 = (m.y != 0);
        const int v2 = (m.z != 0), v3 = (m.w != 0);
        const int mine = v0 + v1 + v2 + v3;
        part[t] = mine;
        __syncthreads();
        for (int off = 1; off < 256; off <<= 1) {
            int y = (t >= off) ? part[t - off] : 0;
            __syncthreads();
            part[t] += y;
            __syncthreads();
        }
        const int ex = part[t] - mine;          // exclusive prefix
        int4 o;
        o.x = v0 ? ex : -1;
        o.y = v1 ? ex + v0 : -1;
        o.z = v2 ? ex + v0 + v1 : -1;
        o.w = v3 ? ex + v0 + v1 + v2 : -1;
        *(int4*)(cpos + b*SEQ + t*4) = o;
        if (t == 255) nvalid[b] = part[255];
        return;
    }
    if (bid < 2048) {
        const size_t i = ((size_t)bid * 256 + threadIdx.x) * 8;
        float4 v0 = *(const float4*)(x + i);
        float4 v1 = *(const float4*)(x + i + 4);
        ushort o[8] = {f2bf(v0.x), f2bf(v0.y), f2bf(v0.z), f2bf(v0.w),
                       f2bf(v1.x), f2bf(v1.y), f2bf(v1.z), f2bf(v1.w)};
        *(uint4*)(xbf + i) = *(uint4*)o;
        return;
    }
    const float* W; ushort* WT; int K, N, bn, bk;
    if (bid < 4096) {
        W = w_t; WT = wtT; K = DIMX; N = TW;
        const int t = bid - 2048;               // 64 x 32 tiles
        bn = (t & 63) * 32; bk = (t >> 6) * 32;
    } else {
        W = w_o; WT = woT; K = DIMX; N = DIMX;
        const int t = bid - 4096;               // 32 x 32 tiles
        bn = (t & 31) * 32; bk = (t >> 5) * 32;
    }
    const int tx = threadIdx.x & 31;
    const int ty = threadIdx.x >> 5;
    #pragma unroll
    for (int i = ty; i < 32; i += 8)
        tile[i][tx] = W[(size_t)(bk + i) * N + bn + tx];
    __syncthreads();
    #pragma unroll
    for (int i = ty; i < 32; i += 8)
        WT[(size_t)(bn + i) * K + bk + tx] = f2bf(tile[tx][i]);
}

// ---------------------------------------------------------------------------
// Shared GEMM body: 128x128 tile, BK=64, DOUBLE-BUFFERED swizzled LDS,
// 2-phase counted-vmcnt pipeline.
// ---------------------------------------------------------------------------
#define GEMM_PROLOGUE(Aptr, Bptr, Kdim)                                        \
    __shared__ __align__(16) ushort lA[2 * 128 * 64];                          \
    __shared__ __align__(16) ushort lB[2 * 128 * 64];                          \
    const int tid  = threadIdx.x;                                              \
    const int lane = tid & 63;                                                 \
    const int wave = tid >> 6;                                                 \
    const int wr   = wave >> 1;                                                \
    const int wc   = wave & 1;                                                 \
    const int rsub = lane >> 3;                   /* row within 8-chunk */     \
    const int scol = ((lane & 7) * 8) ^ ((rsub & 7) << 3);                     \
    const ushort* aP = (Aptr) + (size_t)(bm + wave*32 + rsub) * (Kdim) + scol; \
    const ushort* bP = (Bptr) + (size_t)(bn + wave*32 + rsub) * (Kdim) + scol; \
    ushort* lAw = lA + wave * 2048;                                            \
    ushort* lBw = lB + wave * 2048;                                            \
    const int fr = lane & 15;                                                  \
    const int l4 = lane >> 4;                                                  \
    f32x4 acc[4][4] = {};

#define GSTAGE(buf, k0, Kdim)                                                  \
    do {                                                                       \
        _Pragma("unroll")                                                      \
        for (int c = 0; c < 4; ++c) {                                          \
            GLD16(aP + (size_t)(c*8) * (Kdim) + (k0), lAw + (buf)*8192 + c*512);\
            GLD16(bP + (size_t)(c*8) * (Kdim) + (k0), lBw + (buf)*8192 + c*512);\
        }                                                                      \
    } while (0)

#define GEMM_KLOOP(Kdim)                                                       \
    GSTAGE(0, 0, Kdim);                                                        \
    for (int t = 0; t < (Kdim)/64; ++t) {                                      \
        const int cur = t & 1;                                                 \
        if (t < (Kdim)/64 - 1) {                                               \
            GSTAGE(cur ^ 1, (t + 1) * 64, Kdim);                               \
            asm volatile("s_waitcnt vmcnt(8)" ::: "memory");                   \
        } else {                                                               \
            asm volatile("s_waitcnt vmcnt(0)" ::: "memory");                   \
        }                                                                      \
        __builtin_amdgcn_s_barrier();            /* tile t visible to all */   \
        _Pragma("unroll")                                                      \
        for (int ks = 0; ks < 2; ++ks) {                                       \
            bf16x8 af[4], bfr[4];                                              \
            _Pragma("unroll")                                                  \
            for (int m = 0; m < 4; ++m)                                        \
                af[m] = *(const bf16x8*)&lA[cur*8192 +                         \
                    SW(wr*64 + m*16 + fr, ks*32 + l4*8)];                      \
            _Pragma("unroll")                                                  \
            for (int n = 0; n < 4; ++n)                                        \
                bfr[n] = *(const bf16x8*)&lB[cur*8192 +                        \
                    SW(wc*64 + n*16 + fr, ks*32 + l4*8)];                      \
            _Pragma("unroll")                                                  \
            for (int m = 0; m < 4; ++m)                                        \
                _Pragma("unroll")                                              \
                for (int n = 0; n < 4; ++n)                                    \
                    acc[m][n] = __builtin_amdgcn_mfma_f32_16x16x32_bf16(       \
                        af[m], bfr[n], acc[m][n], 0, 0, 0);                    \
        }                                                                      \
        asm volatile("s_waitcnt lgkmcnt(0)" ::: "memory");                     \
        __builtin_amdgcn_s_barrier();            /* reads done before reuse */ \
    }

// ---------------------------------------------------------------------------
// GEMM1 with split epilogue: cols [0,1024) -> t1b bf16 (q,k);
// cols [1024,2048) -> COMPACTED transposed bf16 Vc[bh][vd][ci] via cpos.
// ---------------------------------------------------------------------------
__global__ __launch_bounds__(256, 2)
void gemm_qkv(const ushort* __restrict__ A, const ushort* __restrict__ BT,
              ushort* __restrict__ t1b, ushort* __restrict__ Vc,
              const int* __restrict__ cpos)
{
    const int2 bij = xcd_swz(TW/128, NPOS/128);
    const int bm = bij.y * 128;
    const int bn = bij.x * 128;
    GEMM_PROLOGUE(A, BT, DIMX)
    GEMM_KLOOP(DIMX)

    const int orow = l4 * 4;
    if (bn < 1024) {
        #pragma unroll
        for (int m = 0; m < 4; ++m)
            #pragma unroll
            for (int n = 0; n < 4; ++n) {
                ushort* dst = t1b + (size_t)(bm + wr * 64 + m * 16 + orow) * 1024
                                  + bn + wc * 64 + n * 16 + fr;
                #pragma unroll
                for (int q = 0; q < 4; ++q)
                    dst[(size_t)q * 1024] = f2bf(acc[m][n][q]);
            }
    } else {
        #pragma unroll
        for (int m = 0; m < 4; ++m)
            #pragma unroll
            for (int n = 0; n < 4; ++n) {
                const int row0 = bm + wr * 64 + m * 16 + orow;   // 4-aligned s
                const int cv   = bn + wc * 64 + n * 16 + fr - 1024;
                const int hh = cv >> 7, vd = cv & 127;
                const int bb = row0 >> 10, ss = row0 & 1023;
                int4 cp = *(const int4*)(cpos + bb*SEQ + ss);
                ushort* vrow = Vc + ((size_t)(bb*NH + hh)*VDD + vd)*SEQ;
                if (cp.x >= 0) vrow[cp.x] = f2bf(acc[m][n][0]);
                if (cp.y >= 0) vrow[cp.y] = f2bf(acc[m][n][1]);
                if (cp.z >= 0) vrow[cp.z] = f2bf(acc[m][n][2]);
                if (cp.w >= 0) vrow[cp.w] = f2bf(acc[m][n][3]);
            }
    }
}

// ---------------------------------------------------------------------------
// GEMM2 re-tiled 64(M)x128(N), BK=64: 512 blocks, 2/CU (r15-verified).
// ---------------------------------------------------------------------------
__global__ __launch_bounds__(256, 2)
void gemm_bf16_mfma(const ushort* __restrict__ A, const ushort* __restrict__ BT,
                    float* __restrict__ C)
{
    __shared__ __align__(16) ushort lA[2 * 64 * 64];     // 16KB
    __shared__ __align__(16) ushort lB[2 * 128 * 64];    // 32KB

    const int2 bij = xcd_swz(DIMX/128, NPOS/64);         // gx=8, gy=64
    const int bm = bij.y * 64;
    const int bn = bij.x * 128;
    const int tid  = threadIdx.x;
    const int lane = tid & 63;
    const int wave = tid >> 6;
    const int wr   = wave >> 1;          // 0..1 (32-row half)
    const int wc   = wave & 1;           // 0..1 (64-col half)
    const int rsub = lane >> 3;
    const int scol = ((lane & 7) * 8) ^ ((rsub & 7) << 3);
    const ushort* aP = A  + (size_t)(bm + wave*16 + rsub) * DIMX + scol;
    const ushort* bP = BT + (size_t)(bn + wave*32 + rsub) * DIMX + scol;
    ushort* lAw = lA + wave * 1024;      // 16 rows x 64
    ushort* lBw = lB + wave * 2048;      // 32 rows x 64
    const int fr = lane & 15;
    const int l4 = lane >> 4;
    f32x4 acc[2][4] = {};

#define GSTAGE2(buf, k0) do {                                                  \
    _Pragma("unroll")                                                          \
    for (int c = 0; c < 2; ++c)                                                \
        GLD16(aP + (size_t)(c*8) * DIMX + (k0), lAw + (buf)*4096 + c*512);     \
    _Pragma("unroll")                                                          \
    for (int c = 0; c < 4; ++c)                                                \
        GLD16(bP + (size_t)(c*8) * DIMX + (k0), lBw + (buf)*8192 + c*512);     \
} while (0)

    GSTAGE2(0, 0);
    for (int t = 0; t < 16; ++t) {
        const int cur = t & 1;
        if (t < 15) {
            GSTAGE2(cur ^ 1, (t + 1) * 64);
            asm volatile("s_waitcnt vmcnt(6)" ::: "memory");   // tile t landed
        } else {
            asm volatile("s_waitcnt vmcnt(0)" ::: "memory");
        }
        __builtin_amdgcn_s_barrier();
        #pragma unroll
        for (int ks = 0; ks < 2; ++ks) {
            bf16x8 af[2], bfr[4];
            #pragma unroll
            for (int m = 0; m < 2; ++m)
                af[m] = *(const bf16x8*)&lA[cur*4096 +
                    SW(wr*32 + m*16 + fr, ks*32 + l4*8)];
            #pragma unroll
            for (int n = 0; n < 4; ++n)
                bfr[n] = *(const bf16x8*)&lB[cur*8192 +
                    SW(wc*64 + n*16 + fr, ks*32 + l4*8)];
            #pragma unroll
            for (int m = 0; m < 2; ++m)
                #pragma unroll
                for (int n = 0; n < 4; ++n)
                    acc[m][n] = __builtin_amdgcn_mfma_f32_16x16x32_bf16(
                        af[m], bfr[n], acc[m][n], 0, 0, 0);
        }
        asm volatile("s_waitcnt lgkmcnt(0)" ::: "memory");
        __builtin_amdgcn_s_barrier();
    }
#undef GSTAGE2

    const int orow = l4 * 4;
    #pragma unroll
    for (int m = 0; m < 2; ++m)
        #pragma unroll
        for (int n = 0; n < 4; ++n) {
            float* dst = C + (size_t)(bm + wr*32 + m*16 + orow) * DIMX
                           + bn + wc*64 + n*16 + fr;
            #pragma unroll
            for (int q = 0; q < 4; ++q)
                dst[(size_t)q * DIMX] = acc[m][n][q];
        }
}

// ---------------------------------------------------------------------------
// Fused masked rotation + bf16 pack, VECTORIZED LDS version (r14-verified).
// ---------------------------------------------------------------------------
__global__ __launch_bounds__(256)
void rotate_pack_qk(const ushort* __restrict__ t1b, const int* __restrict__ mask,
                    const float* __restrict__ rot, ushort* __restrict__ Qb,
                    ushort* __restrict__ Kc, const int* __restrict__ cpos)
{
    const int p   = blockIdx.x;
    const int tid = threadIdx.x;
    const int b = p >> 10, s = p & 1023;
    const bool rotated = (mask[p] != 0);   // block-uniform
    const int cp = cpos[p];                // >=0 iff rotated

    if (!rotated) {
        if (tid < 128) {
            const int h  = tid >> 4;
            const int i4 = (tid & 15) * 4;
            ushort4 q4 = *(const ushort4*)(t1b + (size_t)p*1024 + tid*4);
            ushort o[4];
            o[0] = f2bf(bf2f(q4.x) * SCALE);
            o[1] = f2bf(bf2f(q4.y) * SCALE);
            o[2] = f2bf(bf2f(q4.z) * SCALE);
            o[3] = f2bf(bf2f(q4.w) * SCALE);
            *(ushort4*)&Qb[((size_t)(b*NH + h)*SEQ + s)*HD + i4] = *(ushort4*)o;
        }
        return;
    }

    __shared__ __align__(16) float Rsw [64*64];   // R,  rows XOR-swizzled
    __shared__ __align__(16) float RTsw[64*64];   // R^T, rows XOR-swizzled

    {
        const int r  = tid >> 2;
        const int c0 = (tid & 3) * 16;
        const float* Rg = rot + (size_t)p * 4096 + (size_t)r * 64 + c0;
        #pragma unroll
        for (int u = 0; u < 4; ++u) {
            float4 v = *(const float4*)(Rg + 4*u);
            const int c4 = c0 + 4*u;
            *(float4*)&Rsw[r*64 + (c4 ^ ((r & 15) << 2))] = v;
            RTsw[(c4+0)*64 + (r ^ (((c4+0) & 15) << 2))] = v.x;
            RTsw[(c4+1)*64 + (r ^ (((c4+1) & 15) << 2))] = v.y;
            RTsw[(c4+2)*64 + (r ^ (((c4+2) & 15) << 2))] = v.z;
            RTsw[(c4+3)*64 + (r ^ (((c4+3) & 15) << 2))] = v.w;
        }
    }
    __syncthreads();

    const int i  = tid & 63;
    const int h0 = __builtin_amdgcn_readfirstlane(tid >> 6);   // wave-uniform
    const ushort* qg0 = t1b + (size_t)p*1024 + h0*64;
    const ushort* kg0 = t1b + (size_t)p*1024 + QKD + h0*64;
    const ushort* qg1 = qg0 + 4*64;
    const ushort* kg1 = kg0 + 4*64;

    float aq0 = 0.f, ak0 = 0.f, aq1 = 0.f, ak1 = 0.f;
    const int swk = (i & 15) << 2;
    #pragma unroll
    for (int jc = 0; jc < 16; ++jc) {
        const int j4 = jc * 4;
        const float4 Rv = *(const float4*)&Rsw [i*64 + (j4 ^ swk)];
        const float4 Tv = *(const float4*)&RTsw[i*64 + (j4 ^ swk)];
        const ushort4 qa = *(const ushort4*)(qg0 + j4);
        const ushort4 ka = *(const ushort4*)(kg0 + j4);
        const ushort4 qb = *(const ushort4*)(qg1 + j4);
        const ushort4 kb = *(const ushort4*)(kg1 + j4);
        aq0 = fmaf(Rv.x, bf2f(qa.x), aq0); aq0 = fmaf(Rv.y, bf2f(qa.y), aq0);
        aq0 = fmaf(Rv.z, bf2f(qa.z), aq0); aq0 = fmaf(Rv.w, bf2f(qa.w), aq0);
        ak0 = fmaf(Tv.x, bf2f(ka.x), ak0); ak0 = fmaf(Tv.y, bf2f(ka.y), ak0);
        ak0 = fmaf(Tv.z, bf2f(ka.z), ak0); ak0 = fmaf(Tv.w, bf2f(ka.w), ak0);
        aq1 = fmaf(Rv.x, bf2f(qb.x), aq1); aq1 = fmaf(Rv.y, bf2f(qb.y), aq1);
        aq1 = fmaf(Rv.z, bf2f(qb.z), aq1); aq1 = fmaf(Rv.w, bf2f(qb.w), aq1);
        ak1 = fmaf(Tv.x, bf2f(kb.x), ak1); ak1 = fmaf(Tv.y, bf2f(kb.y), ak1);
        ak1 = fmaf(Tv.z, bf2f(kb.z), ak1); ak1 = fmaf(Tv.w, bf2f(kb.w), ak1);
    }

    Qb[((size_t)(b*NH + h0    )*SEQ + s )*HD + i] = f2bf(aq0 * SCALE);
    Kc[((size_t)(b*NH + h0    )*SEQ + cp)*HD + i] = f2bf(ak0);
    Qb[((size_t)(b*NH + h0 + 4)*SEQ + s )*HD + i] = f2bf(aq1 * SCALE);
    Kc[((size_t)(b*NH + h0 + 4)*SEQ + cp)*HD + i] = f2bf(ak1);
}

// ---------------------------------------------------------------------------
// MFMA Taylor attention on COMPACTED keys (r13-verified): 32x32x16,
// in-register P, split-K wave pairs, counted vmcnt + raw s_barrier.
// ---------------------------------------------------------------------------
__global__ __launch_bounds__(256, 2)
void taylor_attn_mfma(const ushort* __restrict__ Qb, const ushort* __restrict__ Kc,
                      const ushort* __restrict__ Vc, const int* __restrict__ nvalid,
                      ushort* __restrict__ attn)
{
    const int bh  = blockIdx.x;        // 0..31
    const int qt  = blockIdx.y;        // 0..15 (64 q-rows each)
    const int b   = bh >> 3, h = bh & 7;
    const int tid = threadIdx.x;
    const int lane = tid & 63;
    const int wave = tid >> 6;
    const int kh  = wave >> 1;         // key-half
    const int qg  = wave & 1;          // q-group (32 rows)
    const int l31 = lane & 31;
    const int g   = lane >> 5;         // 0..1

    __shared__ __align__(16) ushort smem[32768];
    __shared__ float dpart[64];
    __shared__ float dinv2[64];

    ushort* Ksp = smem + kh * 8192;            // my pair's K dbuf [2][4096]
    ushort* Vsp = smem + 16384 + kh * 8192;    // my pair's V [8192]
    float*  comb = (float*)smem;               // epilogue partial-O (32KB)

    const int nv = nvalid[b];                  // valid keys this batch
    const int T  = (nv + 63) >> 6;             // 64-key tiles
    const int Th = (T + 1) >> 1;               // tiles per key-half

    const ushort* qrow = Qb + ((size_t)bh*SEQ + qt*64 + qg*32 + l31) * HD + g*8;
    bf16x8 qf[4];
    #pragma unroll
    for (int ds = 0; ds < 4; ++ds) qf[ds] = *(const bf16x8*)(qrow + ds*16);

    const int sub  = lane >> 3;
    const int scol = ((lane & 7) * 8) ^ (sub << 3);
    const ushort* Kbase = Kc + (size_t)bh*SEQ*HD;
    const ushort* Vbase = Vc + (size_t)bh*VDD*SEQ;

#define ISSUE_K(buf, ktn) do {                                                 \
    _Pragma("unroll")                                                          \
    for (int i_ = 0; i_ < 4; ++i_)                                             \
        GLD16(Kbase + ((size_t)(ktn)*64 + 8*(qg*4+i_) + sub)*HD + scol,        \
              Ksp + (buf)*4096 + (qg*4+i_)*512);                               \
} while (0)
#define ISSUE_V(ktn) do {                                                      \
    _Pragma("unroll")                                                          \
    for (int i_ = 0; i_ < 8; ++i_)                                             \
        GLD16(Vbase + (size_t)(8*(qg*8+i_) + sub)*SEQ + (ktn)*64 + scol,       \
              Vsp + (qg*8+i_)*512);                                            \
} while (0)

    f32x16 acc[4] = {};
    float dacc = 0.f;

    asm volatile("s_waitcnt vmcnt(0)" ::: "memory");   // qf retired: exact counts
    ISSUE_K(0, kh*Th);

    for (int it = 0; it < Th; ++it) {
        const int kt = kh*Th + it;
        const int cb = it & 1;
        ISSUE_V(kt);                                   // +8 -> 12
        if (it < Th - 1) {
            ISSUE_K(cb ^ 1, kt + 1);                   // +4 -> 16
            asm volatile("s_waitcnt vmcnt(12)" ::: "memory");  // K(it) landed
        } else {
            asm volatile("s_waitcnt vmcnt(8)"  ::: "memory");  // last K landed
        }
        __builtin_amdgcn_s_barrier();

        f32x16 sf0 = {}, sf1 = {};
        __builtin_amdgcn_s_setprio(1);
        #pragma unroll
        for (int ds = 0; ds < 4; ++ds) {
            const int dc = ds*16 + g*8;
            bf16x8 kf0 = *(const bf16x8*)&Ksp[cb*4096 + SW(l31, dc)];
            bf16x8 kf1 = *(const bf16x8*)&Ksp[cb*4096 + SW(32 + l31, dc)];
            sf0 = __builtin_amdgcn_mfma_f32_32x32x16_bf16(kf0, qf[ds], sf0, 0, 0, 0);
            sf1 = __builtin_amdgcn_mfma_f32_32x32x16_bf16(kf1, qf[ds], sf1, 0, 0, 0);
        }
        __builtin_amdgcn_s_setprio(0);

        // ---- transform + pack; validity mask = (key index < nv) inline ----
        const int kb0 = kt*64 + 4*g;
        unsigned w0[8], w1[8];
        float dadd = 0.f;
        #pragma unroll
        for (int rr = 0; rr < 4; ++rr) {
            const int ka = kb0 + 8*rr;          // sf0 keys ka+0..3
            const float ma0 = (ka + 0 < nv) ? 1.f : 0.f;
            const float ma1 = (ka + 1 < nv) ? 1.f : 0.f;
            const float ma2 = (ka + 2 < nv) ? 1.f : 0.f;
            const float ma3 = (ka + 3 < nv) ? 1.f : 0.f;
            const float mb0 = (ka + 32 < nv) ? 1.f : 0.f;
            const float mb1 = (ka + 33 < nv) ? 1.f : 0.f;
            const float mb2 = (ka + 34 < nv) ? 1.f : 0.f;
            const float mb3 = (ka + 35 < nv) ? 1.f : 0.f;
            float s0 = sf0[rr*4+0], s1 = sf0[rr*4+1];
            float s2 = sf0[rr*4+2], s3 = sf0[rr*4+3];
            float c0 = fmaf(fmaf(0.5f*s0, s0, s0), ma0, ma0);
            float c1 = fmaf(fmaf(0.5f*s1, s1, s1), ma1, ma1);
            float c2 = fmaf(fmaf(0.5f*s2, s2, s2), ma2, ma2);
            float c3 = fmaf(fmaf(0.5f*s3, s3, s3), ma3, ma3);
            float t0 = sf1[rr*4+0], t1 = sf1[rr*4+1];
            float t2 = sf1[rr*4+2], t3 = sf1[rr*4+3];
            float d0 = fmaf(fmaf(0.5f*t0, t0, t0), mb0, mb0);
            float d1 = fmaf(fmaf(0.5f*t1, t1, t1), mb1, mb1);
            float d2 = fmaf(fmaf(0.5f*t2, t2, t2), mb2, mb2);
            float d3 = fmaf(fmaf(0.5f*t3, t3, t3), mb3, mb3);
            dadd += ((c0+c1)+(c2+c3)) + ((d0+d1)+(d2+d3));
            w0[rr*2+0] = cvtpk(c0, c1);
            w0[rr*2+1] = cvtpk(c2, c3);
            w1[rr*2+0] = cvtpk(d0, d1);
            w1[rr*2+1] = cvtpk(d2, d3);
        }
        dacc += dadd;
        plswap(w0[0], w0[2]); plswap(w0[1], w0[3]);
        plswap(w0[4], w0[6]); plswap(w0[5], w0[7]);
        plswap(w1[0], w1[2]); plswap(w1[1], w1[3]);
        plswap(w1[4], w1[6]); plswap(w1[5], w1[7]);

        if (it < Th - 1) asm volatile("s_waitcnt vmcnt(4)" ::: "memory");
        else             asm volatile("s_waitcnt vmcnt(0)" ::: "memory");
        __builtin_amdgcn_s_barrier();

        __builtin_amdgcn_s_setprio(1);
        #pragma unroll
        for (int kq = 0; kq < 4; ++kq) {
            union { unsigned u[4]; bf16x8 v; } pu;
            if (kq == 0)      { pu.u[0]=w0[0]; pu.u[1]=w0[1]; pu.u[2]=w0[2]; pu.u[3]=w0[3]; }
            else if (kq == 1) { pu.u[0]=w0[4]; pu.u[1]=w0[5]; pu.u[2]=w0[6]; pu.u[3]=w0[7]; }
            else if (kq == 2) { pu.u[0]=w1[0]; pu.u[1]=w1[1]; pu.u[2]=w1[2]; pu.u[3]=w1[3]; }
            else              { pu.u[0]=w1[4]; pu.u[1]=w1[5]; pu.u[2]=w1[6]; pu.u[3]=w1[7]; }
            const int kcol = kq*16 + g*8;
            acc[0] = __builtin_amdgcn_mfma_f32_32x32x16_bf16(
                pu.v, *(const bf16x8*)&Vsp[SW(      l31, kcol)], acc[0], 0, 0, 0);
            acc[1] = __builtin_amdgcn_mfma_f32_32x32x16_bf16(
                pu.v, *(const bf16x8*)&Vsp[SW( 32 + l31, kcol)], acc[1], 0, 0, 0);
            acc[2] = __builtin_amdgcn_mfma_f32_32x32x16_bf16(
                pu.v, *(const bf16x8*)&Vsp[SW( 64 + l31, kcol)], acc[2], 0, 0, 0);
            acc[3] = __builtin_amdgcn_mfma_f32_32x32x16_bf16(
                pu.v, *(const bf16x8*)&Vsp[SW( 96 + l31, kcol)], acc[3], 0, 0, 0);
        }
        __builtin_amdgcn_s_setprio(0);
        __builtin_amdgcn_s_barrier();   // reads done; safe to overwrite / reuse
    }
#undef ISSUE_K
#undef ISSUE_V

    const float dhalf = dacc + __shfl_xor(dacc, 32);

    if (kh == 1) {
        float* cbp = comb + qg * 4096;                 // [vd 128][q 32] f32
        #pragma unroll
        for (int vb = 0; vb < 4; ++vb)
            #pragma unroll
            for (int rr = 0; rr < 4; ++rr) {
                float4 v = make_float4(acc[vb][rr*4+0], acc[vb][rr*4+1],
                                       acc[vb][rr*4+2], acc[vb][rr*4+3]);
                *(float4*)&cbp[(vb*32 + l31)*32 + 4*g + 8*rr] = v;
            }
        if (lane < 32) dpart[qg*32 + l31] = dhalf;
    }
    __syncthreads();
    if (kh == 0) {
        float* cbp = comb + qg * 4096;
        const float dtot = dhalf + dpart[qg*32 + l31];
        if (lane < 32) dinv2[qg*32 + l31] = 1.f / fmaxf(dtot, 1e-6f);
        #pragma unroll
        for (int vb = 0; vb < 4; ++vb)
            #pragma unroll
            for (int rr = 0; rr < 4; ++rr) {
                float4 v = *(const float4*)&cbp[(vb*32 + l31)*32 + 4*g + 8*rr];
                acc[vb][rr*4+0] += v.x; acc[vb][rr*4+1] += v.y;
                acc[vb][rr*4+2] += v.z; acc[vb][rr*4+3] += v.w;
            }
        float inv[16];
        #pragma unroll
        for (int rr = 0; rr < 4; ++rr) {
            float4 iv = *(const float4*)&dinv2[qg*32 + 8*rr + 4*g];
            inv[rr*4+0] = iv.x; inv[rr*4+1] = iv.y;
            inv[rr*4+2] = iv.z; inv[rr*4+3] = iv.w;
        }
        ushort* obase = attn + ((size_t)(b*SEQ + qt*64 + qg*32)) * DIMX
                      + h*VDD + l31;
        #pragma unroll
        for (int vb = 0; vb < 4; ++vb)
            #pragma unroll
            for (int rr = 0; rr < 4; ++rr)
                #pragma unroll
                for (int j = 0; j < 4; ++j) {
                    const int q = 4*g + 8*rr + j;
                    obase[(size_t)q*DIMX + vb*32] = f2bf(acc[vb][rr*4+j] * inv[rr*4+j]);
                }
    }
}

// ---------------------------------------------------------------------------
extern "C" void kernel_launch(void* const* d_in, const int* in_sizes, int n_in,
                              void* d_out, int out_size, void* d_ws, size_t ws_size,
                              hipStream_t stream)
{
    const float* x    = (const float*)d_in[0];
    const int*   mask = (const int*)d_in[1];
    const float* rot  = (const float*)d_in[2];
    const float* w_t  = (const float*)d_in[3];
    const float* w_o  = (const float*)d_in[4];
    float* out = (float*)d_out;

    // workspace (~38 MB + 16KB):
    // t1b 8MB | xbf/attnbf 8MB | wtT 4MB | woT 2MB | Qb 4MB | Kc 4MB | Vc 8MB
    // | cpos 16KB | nvalid 16B
    ushort* t1b    = (ushort*)d_ws;
    ushort* xbf    = t1b + (size_t)NPOS * 1024;
    ushort* attnbf = xbf;                            // xbf dead after gemm_qkv
    ushort* wtT    = xbf + (size_t)NPOS * DIMX;
    ushort* woT    = wtT + (size_t)TW * DIMX;
    ushort* Qb     = woT + (size_t)DIMX * DIMX;
    ushort* Kc     = Qb  + (size_t)BATCH * NH * SEQ * HD;
    ushort* Vc     = Kc  + (size_t)BATCH * NH * SEQ * HD;
    int*    cpos   = (int*)(Vc + (size_t)BATCH * NH * VDD * SEQ);
    int*    nvalid = cpos + NPOS;

    // 0) fused prep: casts + weight transposes + mask prefix scan
    prep_all<<<5124, 256, 0, stream>>>(x, w_t, w_o, mask, xbf, wtT, woT,
                                       cpos, nvalid);

    // 1) qkv projection: q,k -> t1b bf16; v -> COMPACTED Vc bf16 (scatter)
    gemm_qkv<<<dim3(TW/128, NPOS/128), 256, 0, stream>>>(xbf, wtT, t1b, Vc, cpos);
    // 2) fused masked rotation (vectorized R/R^T LDS) -> Qb, Kc
    rotate_pack_qk<<<NPOS, 256, 0, stream>>>(t1b, mask, rot, Qb, Kc, cpos);
    // 3) fused MFMA Taylor attention on compacted keys -> attnbf
    taylor_attn_mfma<<<dim3(BATCH*NH, SEQ/64), 256, 0, stream>>>(Qb, Kc, Vc,
                                                                 nvalid, attnbf);
    // 4) out = attn @ w_o  (64x128 tiles, 512 blocks)
    gemm_bf16_mfma<<<dim3(DIMX/128, NPOS/64), 256, 0, stream>>>(attnbf, woT, out);
}